// Round 8
// baseline (989.374 us; speedup 1.0000x reference)
//
#include <hip/hip_runtime.h>
#include <math.h>
#include <stdint.h>

typedef __bf16 bf16x8_t __attribute__((ext_vector_type(8)));
typedef float  f32x4_t  __attribute__((ext_vector_type(4)));
typedef unsigned short u16;

// ---- helpers -------------------------------------------------------------

__device__ __forceinline__ u16 f2bf(float f) {
  unsigned u = __float_as_uint(f);
  u += 0x7FFFu + ((u >> 16) & 1u);
  return (u16)(u >> 16);
}

__device__ __forceinline__ void gload_lds16(const u16* gsrc, u16* ldst) {
  // async global->LDS, 16B per lane; LDS dest = wave-uniform base + lane*16
  __builtin_amdgcn_global_load_lds(
      (__attribute__((address_space(1))) void*)(const_cast<u16*>(gsrc)),
      (__attribute__((address_space(3))) void*)(ldst),
      16, 0, 0);
}

// XOR swizzle for 128B rows (64 bf16): byte ^= ((row&7)<<4) == elem ^= ((row&7)<<3)
__device__ __forceinline__ int sw8(int row, int e) { return e ^ ((row & 7) << 3); }
// XOR swizzle for 64B rows (32 bf16): slot(16B) ^= (row>>1)&3  == elem ^= ((row>>1)&3)<<3
__device__ __forceinline__ int sw32(int row, int e) { return e ^ (((row >> 1) & 3) << 3); }

__device__ __forceinline__ void store_out(float* C, long idx, float v) { C[idx] = v; }
__device__ __forceinline__ void store_out(u16* C, long idx, float v) { C[idx] = f2bf(v); }

__device__ __forceinline__ float alibi_slope(int h, int H) {
  int cp2 = 1, lg = 0;
  while (cp2 * 2 <= H) { cp2 *= 2; lg++; }
  if (h < cp2) {
    double e = exp2((double)-(lg - 3));
    return (float)exp2(-e * (double)(h + 1));
  } else {
    double e = exp2((double)-(lg + 1 - 3));
    return (float)exp2(-e * (double)(2 * (h - cp2) + 1));
  }
}

#define FENCE() asm volatile("" ::: "memory")
#define BARRIER() do { FENCE(); __builtin_amdgcn_s_barrier(); \
                       __builtin_amdgcn_sched_barrier(0); FENCE(); } while (0)
#define WAITLGKM() do { asm volatile("s_waitcnt lgkmcnt(0)" ::: "memory"); \
                        __builtin_amdgcn_sched_barrier(0); } while (0)

// ---- elementwise cast f32 -> bf16 ---------------------------------------

__global__ __launch_bounds__(256) void k_cast_bf16(const float* __restrict__ in,
                                                   u16* __restrict__ out, long n) {
  long i = ((long)blockIdx.x * 256 + threadIdx.x) * 4;
  if (i + 3 < n) {
    float4 v = *reinterpret_cast<const float4*>(in + i);
    ushort4 o;
    o.x = f2bf(v.x); o.y = f2bf(v.y); o.z = f2bf(v.z); o.w = f2bf(v.w);
    *reinterpret_cast<ushort4*>(out + i) = o;
  }
}

// ---- transpose + cast: out[z][c][r] = bf16(in[z][r][c]) ------------------

__global__ __launch_bounds__(256) void k_transpose_cast(const float* __restrict__ in,
                                                        u16* __restrict__ out,
                                                        int R, int C) {
  __shared__ float tile[32][33];
  const float* inz = in + (long)blockIdx.z * R * C;
  u16* outz = out + (long)blockIdx.z * R * C;
  const int tx = threadIdx.x & 31, ty = threadIdx.x >> 5;
  const int r0 = blockIdx.y * 32, c0 = blockIdx.x * 32;
#pragma unroll
  for (int i = 0; i < 4; ++i)
    tile[ty + i * 8][tx] = inz[(long)(r0 + ty + i * 8) * C + c0 + tx];
  __syncthreads();
#pragma unroll
  for (int i = 0; i < 4; ++i)
    outz[(long)(c0 + ty + i * 8) * R + r0 + tx] = f2bf(tile[tx][ty + i * 8]);
}

// ---- per-(b,h) transpose of V: [S,Dh slice of D] -> Vt[bh][Dh][S] --------

__global__ __launch_bounds__(256) void k_transpose_v(const u16* __restrict__ V,
                                                     u16* __restrict__ Vt,
                                                     int S, int D, int Dh, int H) {
  __shared__ u16 tile[32][33];
  const int bh = blockIdx.z, b = bh / H, h = bh % H;
  const int tx = threadIdx.x & 31, ty = threadIdx.x >> 5;
  const int s0 = blockIdx.x * 32, d0 = blockIdx.y * 32;
  const u16* vin = V + (long)b * S * D + (long)h * Dh;
#pragma unroll
  for (int i = 0; i < 4; ++i)
    tile[ty + i * 8][tx] = vin[(long)(s0 + ty + i * 8) * D + d0 + tx];
  __syncthreads();
  u16* vout = Vt + (long)bh * Dh * S;
#pragma unroll
  for (int i = 0; i < 4; ++i)
    vout[(long)(d0 + ty + i * 8) * S + s0 + tx] = tile[tx][ty + i * 8];
}

// ---- staging helpers (linear LDS dest + inverse-swizzled global source) --

__device__ __forceinline__ void stage16(const u16* __restrict__ g, long grow0, int K,
                                        int kt, int lr0, u16 (*lds)[64], int lane) {
  const int e = (lane & 7) * 8;
#pragma unroll
  for (int i = 0; i < 2; ++i) {
    const int r = lr0 + i * 8 + (lane >> 3);
    gload_lds16(g + (grow0 + r) * (long)K + kt + (e ^ ((r & 7) << 3)), &lds[lr0 + i * 8][0]);
  }
}

__device__ __forceinline__ void stage8(const u16* __restrict__ g, long grow0, int K,
                                       int kt, int lr0, u16 (*lds)[64], int lane) {
  const int e = (lane & 7) * 8;
  const int r = lr0 + (lane >> 3);
  gload_lds16(g + (grow0 + r) * (long)K + kt + (e ^ ((r & 7) << 3)), &lds[lr0][0]);
}

// 16 rows of 32-elem (64B) rows per instruction; lane -> (row lr0+(lane>>2),
// 16B slot (lane&3)); global source pre-inverse-swizzled with sw32.
__device__ __forceinline__ void stage32(const u16* __restrict__ g, long grow0, int K,
                                        int kt, int lr0, u16 (*lds)[32], int lane) {
  const int r = lr0 + (lane >> 2);
  const int e = (lane & 3) * 8;
  gload_lds16(g + (grow0 + r) * (long)K + kt + sw32(r, e), &lds[lr0][0]);
}

// ---- 256x256 BK=32 bf16 GEMM, 2 blocks/CU (T1+T2+T3+T5), bt pattern ------
// C[M,N] = A[M,K]*Bt[N,K]^T. LDS 64KB (2 blocks/CU co-resident: barrier and
// vmcnt stalls overlap across blocks). 8 waves 2Mx4N, wave tile 128x64.
// Per K-tile: 4 quadrant phases x 8 MFMA; stage B(t+1)@ph1, A(t+1)@ph2;
// single vmcnt(0) at tile end (co-residency hides the drain).

template <typename OUT_T>
__global__ __launch_bounds__(512, 4) void k_gemm32(const u16* __restrict__ A,
                                                   const u16* __restrict__ Bt,
                                                   OUT_T* __restrict__ Cb,
                                                   int M, int N, int K, long matStride,
                                                   float qs) {
  __shared__ u16 As[2][256][32];   // 32KB
  __shared__ u16 Bs[2][256][32];   // 32KB

  const int tid = threadIdx.x, wid = tid >> 6, lane = tid & 63;
  const int wr = wid >> 2, wc = wid & 3;
  const int frow = lane & 15, fk8 = (lane >> 4) * 8;
  const int orow = (lane >> 4) * 4, ocol = lane & 15;

  // T1: bijective XCD-aware swizzle
  const int nwg = gridDim.x * gridDim.y;
  const int orig = blockIdx.y * gridDim.x + blockIdx.x;
  const int q = nwg >> 3, rr = nwg & 7;
  const int xcd = orig & 7, sl = orig >> 3;
  const int wg = (xcd < rr ? xcd * (q + 1) : rr * (q + 1) + (xcd - rr) * q) + sl;
  const int by = wg / gridDim.x, bx = wg % gridDim.x;

  const long abase = (long)by * 256, bbase = (long)bx * 256;

  const int sg0 = wid * 32;   // each wave stages 32 rows (2 instrs) of A and B

  f32x4_t acc[8][4];
#pragma unroll
  for (int m = 0; m < 8; ++m)
#pragma unroll
    for (int n = 0; n < 4; ++n)
#pragma unroll
      for (int r = 0; r < 4; ++r) acc[m][n][r] = 0.f;

  const int nt = K >> 5;

  // prologue: tile 0 into buffer 0
  stage32(Bt, bbase, K, 0, sg0, Bs[0], lane);
  stage32(Bt, bbase, K, 0, sg0 + 16, Bs[0], lane);
  stage32(A, abase, K, 0, sg0, As[0], lane);
  stage32(A, abase, K, 0, sg0 + 16, As[0], lane);
  asm volatile("s_waitcnt vmcnt(0)" ::: "memory");
  BARRIER();

  bf16x8_t a0[4], a1[4], b0[2], b1[2];
  int cur = 0;

  for (int t = 0; t < nt; ++t) {
    const int ktn = (t + 1) << 5;
    const bool hn = (t + 1 < nt);
    const int nb = cur ^ 1;

    // ---- phase 1: (mh0, nh0); stage B(t+1)
#pragma unroll
    for (int m = 0; m < 4; ++m) {
      const int r = wr * 128 + m * 16 + frow;
      a0[m] = *reinterpret_cast<const bf16x8_t*>(&As[cur][r][sw32(r, fk8)]);
    }
#pragma unroll
    for (int n = 0; n < 2; ++n) {
      const int r = wc * 64 + n * 16 + frow;
      b0[n] = *reinterpret_cast<const bf16x8_t*>(&Bs[cur][r][sw32(r, fk8)]);
    }
    if (hn) {
      stage32(Bt, bbase, K, ktn, sg0, Bs[nb], lane);
      stage32(Bt, bbase, K, ktn, sg0 + 16, Bs[nb], lane);
    }
    BARRIER();
    WAITLGKM();
    __builtin_amdgcn_s_setprio(1);
#pragma unroll
    for (int m = 0; m < 4; ++m)
#pragma unroll
      for (int n = 0; n < 2; ++n)
        acc[m][n] = __builtin_amdgcn_mfma_f32_16x16x32_bf16(a0[m], b0[n], acc[m][n], 0, 0, 0);
    __builtin_amdgcn_s_setprio(0);
    BARRIER();

    // ---- phase 2: (mh0, nh1); stage A(t+1)
#pragma unroll
    for (int n = 0; n < 2; ++n) {
      const int r = wc * 64 + 32 + n * 16 + frow;
      b1[n] = *reinterpret_cast<const bf16x8_t*>(&Bs[cur][r][sw32(r, fk8)]);
    }
    if (hn) {
      stage32(A, abase, K, ktn, sg0, As[nb], lane);
      stage32(A, abase, K, ktn, sg0 + 16, As[nb], lane);
    }
    BARRIER();
    WAITLGKM();
    __builtin_amdgcn_s_setprio(1);
#pragma unroll
    for (int m = 0; m < 4; ++m)
#pragma unroll
      for (int n = 0; n < 2; ++n)
        acc[m][2 + n] = __builtin_amdgcn_mfma_f32_16x16x32_bf16(a0[m], b1[n], acc[m][2 + n], 0, 0, 0);
    __builtin_amdgcn_s_setprio(0);
    BARRIER();

    // ---- phase 3: (mh1, nh0)
#pragma unroll
    for (int m = 0; m < 4; ++m) {
      const int r = wr * 128 + 64 + m * 16 + frow;
      a1[m] = *reinterpret_cast<const bf16x8_t*>(&As[cur][r][sw32(r, fk8)]);
    }
    BARRIER();
    WAITLGKM();
    __builtin_amdgcn_s_setprio(1);
#pragma unroll
    for (int m = 0; m < 4; ++m)
#pragma unroll
      for (int n = 0; n < 2; ++n)
        acc[4 + m][n] = __builtin_amdgcn_mfma_f32_16x16x32_bf16(a1[m], b0[n], acc[4 + m][n], 0, 0, 0);
    __builtin_amdgcn_s_setprio(0);
    BARRIER();

    // ---- phase 4: (mh1, nh1); tile-boundary drain
    __builtin_amdgcn_s_setprio(1);
#pragma unroll
    for (int m = 0; m < 4; ++m)
#pragma unroll
      for (int n = 0; n < 2; ++n)
        acc[4 + m][2 + n] = __builtin_amdgcn_mfma_f32_16x16x32_bf16(a1[m], b1[n], acc[4 + m][2 + n], 0, 0, 0);
    __builtin_amdgcn_s_setprio(0);
    if (hn) asm volatile("s_waitcnt vmcnt(0)" ::: "memory");
    BARRIER();

    cur ^= 1;
  }

  // epilogue: col -> (mat, e) split; Q-prescale on cols < 2048
#pragma unroll
  for (int m = 0; m < 8; ++m)
#pragma unroll
    for (int n = 0; n < 4; ++n)
#pragma unroll
      for (int r = 0; r < 4; ++r) {
        const long row = abase + wr * 128 + m * 16 + orow + r;
        const int col = (int)bbase + wc * 64 + n * 16 + ocol;
        const float sc = ((col >> 11) == 0) ? qs : 1.0f;
        const long idx = (long)(col >> 11) * matStride + row * 2048 + (col & 2047);
        store_out(Cb, idx, acc[m][n][r] * sc);
      }
}

// ---- 128x256 2-phase bf16 GEMM (O-proj grid-fill variant, proven R6) -----

template <typename OUT_T>
__global__ __launch_bounds__(512, 2) void k_gemm2(const u16* __restrict__ A,
                                                  const u16* __restrict__ Bt,
                                                  OUT_T* __restrict__ Cb,
                                                  int M, int N, int K, long matStride,
                                                  float qs) {
  __shared__ u16 As[2][128][64];
  __shared__ u16 Bs[2][256][64];

  const int tid = threadIdx.x, wid = tid >> 6, lane = tid & 63;
  const int wr = wid >> 2, wc = wid & 3;
  const int frow = lane & 15, fk8 = (lane >> 4) * 8;
  const int orow = (lane >> 4) * 4, ocol = lane & 15;

  const int nwg = gridDim.x * gridDim.y;
  const int orig = blockIdx.y * gridDim.x + blockIdx.x;
  const int q = nwg >> 3, rr = nwg & 7;
  const int xcd = orig & 7, sl = orig >> 3;
  const int wg = (xcd < rr ? xcd * (q + 1) : rr * (q + 1) + (xcd - rr) * q) + sl;
  const int by = wg / gridDim.x, bx = wg % gridDim.x;

  const long abase = (long)by * 128, bbase = (long)bx * 256;

  const int bg0 = (wid >> 1) * 64 + (wid & 1) * 16;
  const int ag0 = ((wid & 1) << 6) + ((wid >> 1) << 3);

  f32x4_t acc[4][4];
#pragma unroll
  for (int m = 0; m < 4; ++m)
#pragma unroll
    for (int n = 0; n < 4; ++n)
#pragma unroll
      for (int r = 0; r < 4; ++r) acc[m][n][r] = 0.f;

  const int nt = K >> 6;

  stage16(Bt, bbase, K, 0, bg0, Bs[0], lane);
  stage16(Bt, bbase, K, 0, bg0 + 32, Bs[0], lane);
  stage8 (A,  abase, K, 0, ag0, As[0], lane);
  stage8 (A,  abase, K, 0, ag0 + 32, As[0], lane);
  asm volatile("s_waitcnt vmcnt(1)" ::: "memory");
  BARRIER();

  bf16x8_t bfr[4][2], afr[2][2];
  int cur = 0;

  for (int t = 0; t < nt; ++t) {
    const int ktn = (t + 1) << 6;
    const bool hn = (t + 1 < nt);
    const int nb = cur ^ 1;

#pragma unroll
    for (int n = 0; n < 4; ++n) {
      const int r = wc * 64 + n * 16 + frow;
      bfr[n][0] = *reinterpret_cast<const bf16x8_t*>(&Bs[cur][r][sw8(r, fk8)]);
      bfr[n][1] = *reinterpret_cast<const bf16x8_t*>(&Bs[cur][r][sw8(r, 32 + fk8)]);
    }
#pragma unroll
    for (int m = 0; m < 2; ++m) {
      const int r = wr * 64 + m * 16 + frow;
      afr[m][0] = *reinterpret_cast<const bf16x8_t*>(&As[cur][r][sw8(r, fk8)]);
      afr[m][1] = *reinterpret_cast<const bf16x8_t*>(&As[cur][r][sw8(r, 32 + fk8)]);
    }
    if (hn) {
      stage16(Bt, bbase, K, ktn, bg0, Bs[nb], lane);
      stage16(Bt, bbase, K, ktn, bg0 + 32, Bs[nb], lane);
    }
    BARRIER();
    WAITLGKM();
    __builtin_amdgcn_s_setprio(1);
#pragma unroll
    for (int m = 0; m < 2; ++m)
#pragma unroll
      for (int n = 0; n < 4; ++n) {
        acc[m][n] = __builtin_amdgcn_mfma_f32_16x16x32_bf16(afr[m][0], bfr[n][0], acc[m][n], 0, 0, 0);
        acc[m][n] = __builtin_amdgcn_mfma_f32_16x16x32_bf16(afr[m][1], bfr[n][1], acc[m][n], 0, 0, 0);
      }
    __builtin_amdgcn_s_setprio(0);
    if (hn) asm volatile("s_waitcnt vmcnt(4)" ::: "memory");
    else    asm volatile("s_waitcnt vmcnt(0)" ::: "memory");
    BARRIER();

#pragma unroll
    for (int m = 0; m < 2; ++m) {
      const int r = wr * 64 + 32 + m * 16 + frow;
      afr[m][0] = *reinterpret_cast<const bf16x8_t*>(&As[cur][r][sw8(r, fk8)]);
      afr[m][1] = *reinterpret_cast<const bf16x8_t*>(&As[cur][r][sw8(r, 32 + fk8)]);
    }
    if (hn) {
      stage8(A, abase, K, ktn, ag0, As[nb], lane);
      stage8(A, abase, K, ktn, ag0 + 32, As[nb], lane);
    }
    BARRIER();
    WAITLGKM();
    __builtin_amdgcn_s_setprio(1);
#pragma unroll
    for (int m = 0; m < 2; ++m)
#pragma unroll
      for (int n = 0; n < 4; ++n) {
        acc[2 + m][n] = __builtin_amdgcn_mfma_f32_16x16x32_bf16(afr[m][0], bfr[n][0], acc[2 + m][n], 0, 0, 0);
        acc[2 + m][n] = __builtin_amdgcn_mfma_f32_16x16x32_bf16(afr[m][1], bfr[n][1], acc[2 + m][n], 0, 0, 0);
      }
    __builtin_amdgcn_s_setprio(0);
    if (hn) asm volatile("s_waitcnt vmcnt(1)" ::: "memory");
    BARRIER();

    cur ^= 1;
  }

#pragma unroll
  for (int m = 0; m < 4; ++m)
#pragma unroll
    for (int n = 0; n < 4; ++n)
#pragma unroll
      for (int r = 0; r < 4; ++r) {
        const long row = abase + wr * 64 + m * 16 + orow + r;
        const int col = (int)bbase + wc * 64 + n * 16 + ocol;
        const float sc = ((col >> 11) == 0) ? qs : 1.0f;
        const long idx = (long)(col >> 11) * matStride + row * 2048 + (col & 2047);
        store_out(Cb, idx, acc[m][n][r] * sc);
      }
}

// ---- flash attention, QBLK=64, log2-domain softmax (proven R5) -----------

__global__ __launch_bounds__(256) void k_attn(const u16* __restrict__ Q,
                                              const u16* __restrict__ Kb,
                                              const u16* __restrict__ Vt,
                                              u16* __restrict__ Out,
                                              int B, int S, int H, int D,
                                              float log2e) {
  __shared__ u16 Ks[64][128];
  __shared__ u16 Vs[128][64];
  __shared__ u16 Ps[64][64];

  const int tid = threadIdx.x, wid = tid >> 6, lane = tid & 63;

  const int nq = gridDim.x, nbh = gridDim.y;
  const int lin = blockIdx.x + nq * blockIdx.y;
  const int qb0 = lin / nbh;
  const int bh  = lin % nbh;
  const int qb  = (qb0 < nq / 2) ? qb0 : (nq + nq / 2 - 1 - qb0);

  const int b = bh / H, h = bh % H;
  const int Dh = D / H;

  const float slope2 = alibi_slope(h, H) * log2e;
  const long qrow0 = (long)b * S + qb * 64 + wid * 16;

  const int frow = lane & 15;
  const int fk8  = (lane >> 4) * 8;
  const int orow = (lane >> 4) * 4;
  const int ocol = lane & 15;

  bf16x8_t aq[4];
#pragma unroll
  for (int kk = 0; kk < 4; ++kk)
    aq[kk] = *reinterpret_cast<const bf16x8_t*>(
        Q + (qrow0 + frow) * (long)D + h * Dh + kk * 32 + fk8);

  float cw[4];
#pragma unroll
  for (int n = 0; n < 4; ++n) cw[n] = slope2 * (float)(n * 16 + ocol);

  f32x4_t oacc[8];
#pragma unroll
  for (int no = 0; no < 8; ++no)
#pragma unroll
    for (int r = 0; r < 4; ++r) oacc[no][r] = 0.f;

  float Mrun[4], lrun[4];
#pragma unroll
  for (int r = 0; r < 4; ++r) { Mrun[r] = -3.0e38f; lrun[r] = 0.f; }

  const u16* kbase = Kb + (long)b * S * D + h * Dh;
  const u16* vbase = Vt + (long)bh * Dh * S;

  const int ntile = qb + 1;

  for (int kt = 0; kt < ntile; ++kt) {
    __syncthreads();
#pragma unroll
    for (int i = 0; i < 4; ++i) {
      const int lr = i * 16 + wid * 4;
      const int r  = lr + (lane >> 4);
      gload_lds16(kbase + ((long)kt * 64 + r) * (long)D + sw8(r, (lane & 15) * 8), &Ks[lr][0]);
    }
#pragma unroll
    for (int i = 0; i < 4; ++i) {
      const int lr = i * 32 + wid * 8;
      const int r  = lr + (lane >> 3);
      gload_lds16(vbase + (long)r * S + kt * 64 + sw8(r, (lane & 7) * 8), &Vs[lr][0]);
    }
    __syncthreads();

    f32x4_t sacc[4];
#pragma unroll
    for (int n = 0; n < 4; ++n)
#pragma unroll
      for (int r = 0; r < 4; ++r) sacc[n][r] = 0.f;

#pragma unroll
    for (int kk = 0; kk < 4; ++kk) {
      bf16x8_t bk[4];
#pragma unroll
      for (int n = 0; n < 4; ++n) {
        const int krow = n * 16 + frow;
        bk[n] = *reinterpret_cast<const bf16x8_t*>(&Ks[krow][sw8(krow, kk * 32 + fk8)]);
      }
#pragma unroll
      for (int n = 0; n < 4; ++n)
        sacc[n] = __builtin_amdgcn_mfma_f32_16x16x32_bf16(aq[kk], bk[n], sacc[n], 0, 0, 0);
    }

    const float tb = slope2 * (float)(kt << 6);
    float cbn[4];
#pragma unroll
    for (int n = 0; n < 4; ++n) cbn[n] = tb + cw[n];

    float tmax[4];
#pragma unroll
    for (int r = 0; r < 4; ++r) tmax[r] = -3.0e38f;

    if (kt == qb) {
#pragma unroll
      for (int n = 0; n < 4; ++n)
#pragma unroll
        for (int r = 0; r < 4; ++r) {
          float v = sacc[n][r] + cbn[n];
          v = (n * 16 + ocol <= wid * 16 + orow + r) ? v : -1.0e30f;
          sacc[n][r] = v;
          tmax[r] = fmaxf(tmax[r], v);
        }
    } else {
#pragma unroll
      for (int n = 0; n < 4; ++n)
#pragma unroll
        for (int r = 0; r < 4; ++r) {
          const float v = sacc[n][r] + cbn[n];
          sacc[n][r] = v;
          tmax[r] = fmaxf(tmax[r], v);
        }
    }
#pragma unroll
    for (int r = 0; r < 4; ++r) {
      float t = tmax[r];
      t = fmaxf(t, __shfl_xor(t, 1));
      t = fmaxf(t, __shfl_xor(t, 2));
      t = fmaxf(t, __shfl_xor(t, 4));
      t = fmaxf(t, __shfl_xor(t, 8));
      tmax[r] = t;
    }

#pragma unroll
    for (int r = 0; r < 4; ++r) {
      const float mnew = fmaxf(Mrun[r], tmax[r]);
      const float alpha = exp2f(Mrun[r] - mnew);
      Mrun[r] = mnew;
      lrun[r] *= alpha;
#pragma unroll
      for (int no = 0; no < 8; ++no) oacc[no][r] *= alpha;
    }

    float tsum[4];
#pragma unroll
    for (int r = 0; r < 4; ++r) tsum[r] = 0.f;
#pragma unroll
    for (int n = 0; n < 4; ++n)
#pragma unroll
      for (int r = 0; r < 4; ++r) {
        const float p = exp2f(sacc[n][r] - Mrun[r]);
        tsum[r] += p;
        const int prow = wid * 16 + orow + r;
        Ps[prow][sw8(prow, n * 16 + ocol)] = f2bf(p);
      }
#pragma unroll
    for (int r = 0; r < 4; ++r) {
      float t = tsum[r];
      t += __shfl_xor(t, 1);
      t += __shfl_xor(t, 2);
      t += __shfl_xor(t, 4);
      t += __shfl_xor(t, 8);
      lrun[r] += t;
    }

    __syncthreads();

#pragma unroll
    for (int kk = 0; kk < 2; ++kk) {
      const int prow = wid * 16 + frow;
      bf16x8_t pa = *reinterpret_cast<const bf16x8_t*>(&Ps[prow][sw8(prow, kk * 32 + fk8)]);
#pragma unroll
      for (int no = 0; no < 8; ++no) {
        const int vrow = no * 16 + frow;
        bf16x8_t bv = *reinterpret_cast<const bf16x8_t*>(&Vs[vrow][sw8(vrow, kk * 32 + fk8)]);
        oacc[no] = __builtin_amdgcn_mfma_f32_16x16x32_bf16(pa, bv, oacc[no], 0, 0, 0);
      }
    }
  }

#pragma unroll
  for (int r = 0; r < 4; ++r) {
    const float rl = 1.0f / lrun[r];
    const long trow = qrow0 + orow + r;
#pragma unroll
    for (int no = 0; no < 8; ++no)
      Out[trow * (long)D + h * Dh + no * 16 + ocol] = f2bf(oacc[no][r] * rl);
  }
}

// ---- launch --------------------------------------------------------------

extern "C" void kernel_launch(void* const* d_in, const int* in_sizes, int n_in,
                              void* d_out, int out_size, void* d_ws, size_t ws_size,
                              hipStream_t stream) {
  const float* hs   = (const float*)d_in[0];
  const float* qkvw = (const float*)d_in[1];
  const float* ow   = (const float*)d_in[2];

  const int D = 2048, B = 2, H = 16;
  const long TD = (long)in_sizes[0];   // T*D = 8388608
  const long DD = (long)in_sizes[2];   // D*D = 4194304
  const int T = (int)(TD / D);         // 4096
  const int S = T / B;                 // 2048
  const int Dh = D / H;                // 128
  const float log2e = 1.44269504f;
  const float qs = (1.0f / sqrtf((float)Dh)) * log2e;  // Q prescale

  u16* ws  = (u16*)d_ws;
  u16* hsb = ws;                  // TD    (later reused as attn)
  u16* wt  = ws + TD;             // 3*DD  (later reused as vt)
  u16* owt = wt + 3 * DD;         // DD
  u16* qkv = owt + DD;            // 3*TD  [Q | K | V]
  u16* vt   = wt;                 // TD    (overlay; wt dead after QKV GEMM)
  u16* attn = hsb;                // TD    (overlay; hsb dead after QKV GEMM)

  // 1) hidden -> bf16
  k_cast_bf16<<<dim3((unsigned)(TD / 1024)), 256, 0, stream>>>(hs, hsb, TD);
  // 2) qkv weights: cast + transpose to [3][E][D] (== fused Bt [6144][2048])
  k_transpose_cast<<<dim3(D / 32, D / 32, 3), 256, 0, stream>>>(qkvw, wt, D, D);
  // 3) o_proj weight: cast + transpose to [E][D]
  k_transpose_cast<<<dim3(D / 32, D / 32, 1), 256, 0, stream>>>(ow, owt, D, D);
  // 4) fused QKV projection, BK=32 2-blocks/CU (384 blocks = 1 round)
  k_gemm32<u16><<<dim3((3 * D) / 256, T / 256), 512, 0, stream>>>(
      hsb, wt, qkv, T, 3 * D, D, TD, qs);
  // 5) V -> Vt[bh][Dh][S]
  k_transpose_v<<<dim3(S / 32, Dh / 32, B * H), 256, 0, stream>>>(
      qkv + 2 * TD, vt, S, D, Dh, H);
  // 6) attention (QBLK=64, log2 domain)
  k_attn<<<dim3(S / 64, B * H), 256, 0, stream>>>(
      qkv, qkv + TD, vt, attn, B, S, H, D, log2e);
  // 7) output projection -> f32 d_out (128x256 tiles: 256 blocks = 1 round)
  k_gemm2<float><<<dim3(D / 256, T / 128), 512, 0, stream>>>(
      attn, owt, (float*)d_out, T, D, D, 0L, 1.0f);
}

// Round 9
// 300.516 us; speedup vs baseline: 3.2923x; 3.2923x over previous
//
#include <hip/hip_runtime.h>
#include <math.h>
#include <stdint.h>

typedef __bf16 bf16x8_t __attribute__((ext_vector_type(8)));
typedef float  f32x4_t  __attribute__((ext_vector_type(4)));
typedef unsigned short u16;

// ---- helpers -------------------------------------------------------------

__device__ __forceinline__ u16 f2bf(float f) {
  unsigned u = __float_as_uint(f);
  u += 0x7FFFu + ((u >> 16) & 1u);
  return (u16)(u >> 16);
}

__device__ __forceinline__ void gload_lds16(const u16* gsrc, u16* ldst) {
  // async global->LDS, 16B per lane; LDS dest = wave-uniform base + lane*16
  __builtin_amdgcn_global_load_lds(
      (__attribute__((address_space(1))) void*)(const_cast<u16*>(gsrc)),
      (__attribute__((address_space(3))) void*)(ldst),
      16, 0, 0);
}

// XOR swizzle for 128B rows (64 bf16): byte ^= ((row&7)<<4) == elem ^= ((row&7)<<3)
__device__ __forceinline__ int sw8(int row, int e) { return e ^ ((row & 7) << 3); }

__device__ __forceinline__ void store_out(float* C, long idx, float v) { C[idx] = v; }
__device__ __forceinline__ void store_out(u16* C, long idx, float v) { C[idx] = f2bf(v); }

__device__ __forceinline__ float alibi_slope(int h, int H) {
  int cp2 = 1, lg = 0;
  while (cp2 * 2 <= H) { cp2 *= 2; lg++; }
  if (h < cp2) {
    double e = exp2((double)-(lg - 3));
    return (float)exp2(-e * (double)(h + 1));
  } else {
    double e = exp2((double)-(lg + 1 - 3));
    return (float)exp2(-e * (double)(2 * (h - cp2) + 1));
  }
}

#define FENCE() asm volatile("" ::: "memory")
#define BARRIER() do { FENCE(); __builtin_amdgcn_s_barrier(); \
                       __builtin_amdgcn_sched_barrier(0); FENCE(); } while (0)
#define WAITLGKM() do { asm volatile("s_waitcnt lgkmcnt(0)" ::: "memory"); \
                        __builtin_amdgcn_sched_barrier(0); } while (0)

// ---- elementwise cast f32 -> bf16 ---------------------------------------

__global__ __launch_bounds__(256) void k_cast_bf16(const float* __restrict__ in,
                                                   u16* __restrict__ out, long n) {
  long i = ((long)blockIdx.x * 256 + threadIdx.x) * 4;
  if (i + 3 < n) {
    float4 v = *reinterpret_cast<const float4*>(in + i);
    ushort4 o;
    o.x = f2bf(v.x); o.y = f2bf(v.y); o.z = f2bf(v.z); o.w = f2bf(v.w);
    *reinterpret_cast<ushort4*>(out + i) = o;
  }
}

// ---- transpose + cast: out[z][c][r] = bf16(in[z][r][c]) ------------------

__global__ __launch_bounds__(256) void k_transpose_cast(const float* __restrict__ in,
                                                        u16* __restrict__ out,
                                                        int R, int C) {
  __shared__ float tile[32][33];
  const float* inz = in + (long)blockIdx.z * R * C;
  u16* outz = out + (long)blockIdx.z * R * C;
  const int tx = threadIdx.x & 31, ty = threadIdx.x >> 5;
  const int r0 = blockIdx.y * 32, c0 = blockIdx.x * 32;
#pragma unroll
  for (int i = 0; i < 4; ++i)
    tile[ty + i * 8][tx] = inz[(long)(r0 + ty + i * 8) * C + c0 + tx];
  __syncthreads();
#pragma unroll
  for (int i = 0; i < 4; ++i)
    outz[(long)(c0 + ty + i * 8) * R + r0 + tx] = f2bf(tile[tx][ty + i * 8]);
}

// ---- per-(b,h) transpose of V: [S,Dh slice of D] -> Vt[bh][Dh][S] --------

__global__ __launch_bounds__(256) void k_transpose_v(const u16* __restrict__ V,
                                                     u16* __restrict__ Vt,
                                                     int S, int D, int Dh, int H) {
  __shared__ u16 tile[32][33];
  const int bh = blockIdx.z, b = bh / H, h = bh % H;
  const int tx = threadIdx.x & 31, ty = threadIdx.x >> 5;
  const int s0 = blockIdx.x * 32, d0 = blockIdx.y * 32;
  const u16* vin = V + (long)b * S * D + (long)h * Dh;
#pragma unroll
  for (int i = 0; i < 4; ++i)
    tile[ty + i * 8][tx] = vin[(long)(s0 + ty + i * 8) * D + d0 + tx];
  __syncthreads();
  u16* vout = Vt + (long)bh * Dh * S;
#pragma unroll
  for (int i = 0; i < 4; ++i)
    vout[(long)(d0 + ty + i * 8) * S + s0 + tx] = tile[tx][ty + i * 8];
}

// ---- staging helper (linear LDS dest + inverse-swizzled global source) ---

__device__ __forceinline__ void stage16(const u16* __restrict__ g, long grow0, int K,
                                        int kt, int lr0, u16 (*lds)[64], int lane) {
  const int e = (lane & 7) * 8;
#pragma unroll
  for (int i = 0; i < 2; ++i) {
    const int r = lr0 + i * 8 + (lane >> 3);
    gload_lds16(g + (grow0 + r) * (long)K + kt + (e ^ ((r & 7) << 3)), &lds[lr0 + i * 8][0]);
  }
}

// ---- 256x256 8-phase bf16 GEMM (T1+T2+T3+T4+T5), bt pattern --------------
// C[M,N] = A[M,K] * Bt[N,K]^T. qs scales cols 0..2047 of the output (used
// to prescale Q by sm_scale*log2e for the log2-domain attention softmax).
// Proven R5/R6: 131us on QKV (M=4096,N=6144,K=2048), 0 bank conflicts.

template <typename OUT_T>
__global__ __launch_bounds__(512, 2) void k_gemm8(const u16* __restrict__ A,
                                                  const u16* __restrict__ Bt,
                                                  OUT_T* __restrict__ Cb,
                                                  int M, int N, int K, long matStride,
                                                  float qs) {
  __shared__ u16 As[2][256][64];
  __shared__ u16 Bs[2][256][64];

  const int tid = threadIdx.x, wid = tid >> 6, lane = tid & 63;
  const int wr = wid >> 2, wc = wid & 3;
  const int frow = lane & 15, fk8 = (lane >> 4) * 8;
  const int orow = (lane >> 4) * 4, ocol = lane & 15;

  // T1: bijective XCD-aware swizzle
  const int nwg = gridDim.x * gridDim.y;
  const int orig = blockIdx.y * gridDim.x + blockIdx.x;
  const int q = nwg >> 3, rr = nwg & 7;
  const int xcd = orig & 7, sl = orig >> 3;
  const int wg = (xcd < rr ? xcd * (q + 1) : rr * (q + 1) + (xcd - rr) * q) + sl;
  const int by = wg / gridDim.x, bx = wg % gridDim.x;

  const long abase = (long)by * 256, bbase = (long)bx * 256;

  const int bg0 = (wid >> 1) * 64 + (wid & 1) * 16;
  const int ag0 = (wid >> 2) * 128 + (wid & 3) * 16;

  f32x4_t acc[8][4];
#pragma unroll
  for (int m = 0; m < 8; ++m)
#pragma unroll
    for (int n = 0; n < 4; ++n)
#pragma unroll
      for (int r = 0; r < 4; ++r) acc[m][n][r] = 0.f;

  const int nt = K >> 6;

  stage16(Bt, bbase, K, 0, bg0, Bs[0], lane);
  stage16(Bt, bbase, K, 0, bg0 + 32, Bs[0], lane);
  stage16(A, abase, K, 0, ag0, As[0], lane);
  stage16(A, abase, K, 0, ag0 + 64, As[0], lane);
  asm volatile("s_waitcnt vmcnt(2)" ::: "memory");
  BARRIER();

  bf16x8_t afr[4][2], bfr[4][2];
  int cur = 0;

  for (int t = 0; t < nt; ++t) {
    const int ktn = (t + 1) << 6;
    const bool hn = (t + 1 < nt);
    const int nb = cur ^ 1;

    // ---- phase 1
#pragma unroll
    for (int m = 0; m < 4; ++m) {
      const int r = wr * 128 + m * 16 + frow;
      afr[m][0] = *reinterpret_cast<const bf16x8_t*>(&As[cur][r][sw8(r, fk8)]);
      afr[m][1] = *reinterpret_cast<const bf16x8_t*>(&As[cur][r][sw8(r, 32 + fk8)]);
    }
#pragma unroll
    for (int n = 0; n < 2; ++n) {
      const int r = wc * 64 + n * 16 + frow;
      bfr[n][0] = *reinterpret_cast<const bf16x8_t*>(&Bs[cur][r][sw8(r, fk8)]);
      bfr[n][1] = *reinterpret_cast<const bf16x8_t*>(&Bs[cur][r][sw8(r, 32 + fk8)]);
    }
    if (hn) stage16(Bt, bbase, K, ktn, bg0, Bs[nb], lane);
    BARRIER();
    WAITLGKM();
    __builtin_amdgcn_s_setprio(1);
#pragma unroll
    for (int m = 0; m < 4; ++m)
#pragma unroll
      for (int n = 0; n < 2; ++n) {
        acc[m][n] = __builtin_amdgcn_mfma_f32_16x16x32_bf16(afr[m][0], bfr[n][0], acc[m][n], 0, 0, 0);
        acc[m][n] = __builtin_amdgcn_mfma_f32_16x16x32_bf16(afr[m][1], bfr[n][1], acc[m][n], 0, 0, 0);
      }
    __builtin_amdgcn_s_setprio(0);
    BARRIER();

    // ---- phase 2
#pragma unroll
    for (int n = 0; n < 2; ++n) {
      const int r = wc * 64 + 32 + n * 16 + frow;
      bfr[2 + n][0] = *reinterpret_cast<const bf16x8_t*>(&Bs[cur][r][sw8(r, fk8)]);
      bfr[2 + n][1] = *reinterpret_cast<const bf16x8_t*>(&Bs[cur][r][sw8(r, 32 + fk8)]);
    }
    if (hn) stage16(Bt, bbase, K, ktn, bg0 + 32, Bs[nb], lane);
    BARRIER();
    WAITLGKM();
    __builtin_amdgcn_s_setprio(1);
#pragma unroll
    for (int m = 0; m < 4; ++m)
#pragma unroll
      for (int n = 0; n < 2; ++n) {
        acc[m][2 + n] = __builtin_amdgcn_mfma_f32_16x16x32_bf16(afr[m][0], bfr[2 + n][0], acc[m][2 + n], 0, 0, 0);
        acc[m][2 + n] = __builtin_amdgcn_mfma_f32_16x16x32_bf16(afr[m][1], bfr[2 + n][1], acc[m][2 + n], 0, 0, 0);
      }
    __builtin_amdgcn_s_setprio(0);
    if (hn) asm volatile("s_waitcnt vmcnt(4)" ::: "memory");
    else    asm volatile("s_waitcnt vmcnt(0)" ::: "memory");
    BARRIER();

    // ---- phase 3
#pragma unroll
    for (int m = 0; m < 4; ++m) {
      const int r = wr * 128 + 64 + m * 16 + frow;
      afr[m][0] = *reinterpret_cast<const bf16x8_t*>(&As[cur][r][sw8(r, fk8)]);
      afr[m][1] = *reinterpret_cast<const bf16x8_t*>(&As[cur][r][sw8(r, 32 + fk8)]);
    }
    if (hn) stage16(A, abase, K, ktn, ag0, As[nb], lane);
    BARRIER();
    WAITLGKM();
    __builtin_amdgcn_s_setprio(1);
#pragma unroll
    for (int m = 0; m < 4; ++m)
#pragma unroll
      for (int n = 0; n < 2; ++n) {
        acc[4 + m][n] = __builtin_amdgcn_mfma_f32_16x16x32_bf16(afr[m][0], bfr[n][0], acc[4 + m][n], 0, 0, 0);
        acc[4 + m][n] = __builtin_amdgcn_mfma_f32_16x16x32_bf16(afr[m][1], bfr[n][1], acc[4 + m][n], 0, 0, 0);
      }
    __builtin_amdgcn_s_setprio(0);
    BARRIER();

    // ---- phase 4
    if (hn) stage16(A, abase, K, ktn, ag0 + 64, As[nb], lane);
    __builtin_amdgcn_s_setprio(1);
#pragma unroll
    for (int m = 0; m < 4; ++m)
#pragma unroll
      for (int n = 0; n < 2; ++n) {
        acc[4 + m][2 + n] = __builtin_amdgcn_mfma_f32_16x16x32_bf16(afr[m][0], bfr[2 + n][0], acc[4 + m][2 + n], 0, 0, 0);
        acc[4 + m][2 + n] = __builtin_amdgcn_mfma_f32_16x16x32_bf16(afr[m][1], bfr[2 + n][1], acc[4 + m][2 + n], 0, 0, 0);
      }
    __builtin_amdgcn_s_setprio(0);
    if (hn) asm volatile("s_waitcnt vmcnt(2)" ::: "memory");
    BARRIER();

    cur ^= 1;
  }

#pragma unroll
  for (int m = 0; m < 8; ++m)
#pragma unroll
    for (int n = 0; n < 4; ++n)
#pragma unroll
      for (int r = 0; r < 4; ++r) {
        const long row = abase + wr * 128 + m * 16 + orow + r;
        const int col = (int)bbase + wc * 64 + n * 16 + ocol;
        const float sc = ((col >> 11) == 0) ? qs : 1.0f;
        const long idx = (long)(col >> 11) * matStride + row * 2048 + (col & 2047);
        store_out(Cb, idx, acc[m][n][r] * sc);
      }
}

// ---- m97-style 128x128 bf16 GEMM (proven R2: 631 TF avg) -----------------
// 4 waves (2x2), wave 64x64 = 4x4 frags. 32KB LDS -> multiple blocks/CU;
// barrier drains overlap across co-resident blocks (m114). Unswizzled
// (T2 null at 128^2 2-phase per regime gate).

template <typename OUT_T>
__global__ __launch_bounds__(256) void k_gemm_bt(const u16* __restrict__ A,
                                                 const u16* __restrict__ Bt,
                                                 OUT_T* __restrict__ C,
                                                 int M, int N, int K) {
  __shared__ u16 As[128][64];
  __shared__ u16 Bs[128][64];
  const int tid = threadIdx.x;
  const int wid = tid >> 6, lane = tid & 63;
  const int wr = wid >> 1, wc = wid & 1;

  const long abase = (long)blockIdx.y * 128;
  const long bbase = (long)blockIdx.x * 128;

  f32x4_t acc[4][4];
#pragma unroll
  for (int m = 0; m < 4; ++m)
#pragma unroll
    for (int n = 0; n < 4; ++n)
#pragma unroll
      for (int r = 0; r < 4; ++r) acc[m][n][r] = 0.f;

  const int srow = lane >> 3;
  const int scol = (lane & 7) * 8;

  for (int kt = 0; kt < K; kt += 64) {
    __syncthreads();
#pragma unroll
    for (int i = 0; i < 4; ++i) {
      const int lr = i * 32 + wid * 8;
      gload_lds16(A  + (abase + lr + srow) * (long)K + kt + scol, &As[lr][0]);
      gload_lds16(Bt + (bbase + lr + srow) * (long)K + kt + scol, &Bs[lr][0]);
    }
    __syncthreads();

    const int frow = lane & 15;
    const int fk8  = (lane >> 4) * 8;
#pragma unroll
    for (int kk = 0; kk < 2; ++kk) {
      bf16x8_t af[4], bfr[4];
#pragma unroll
      for (int m = 0; m < 4; ++m)
        af[m] = *reinterpret_cast<const bf16x8_t*>(&As[wr * 64 + m * 16 + frow][kk * 32 + fk8]);
#pragma unroll
      for (int n = 0; n < 4; ++n)
        bfr[n] = *reinterpret_cast<const bf16x8_t*>(&Bs[wc * 64 + n * 16 + frow][kk * 32 + fk8]);
#pragma unroll
      for (int m = 0; m < 4; ++m)
#pragma unroll
        for (int n = 0; n < 4; ++n)
          acc[m][n] = __builtin_amdgcn_mfma_f32_16x16x32_bf16(af[m], bfr[n], acc[m][n], 0, 0, 0);
    }
  }

  const int orow = (lane >> 4) * 4;
  const int ocol = lane & 15;
#pragma unroll
  for (int m = 0; m < 4; ++m)
#pragma unroll
    for (int n = 0; n < 4; ++n)
#pragma unroll
      for (int r = 0; r < 4; ++r) {
        const long row = abase + wr * 64 + m * 16 + orow + r;
        const long col = bbase + wc * 64 + n * 16 + ocol;
        store_out(C, row * (long)N + col, acc[m][n][r]);
      }
}

// ---- flash attention, QBLK=64, log2-domain softmax (proven R5) -----------

__global__ __launch_bounds__(256) void k_attn(const u16* __restrict__ Q,
                                              const u16* __restrict__ Kb,
                                              const u16* __restrict__ Vt,
                                              u16* __restrict__ Out,
                                              int B, int S, int H, int D,
                                              float log2e) {
  __shared__ u16 Ks[64][128];
  __shared__ u16 Vs[128][64];
  __shared__ u16 Ps[64][64];

  const int tid = threadIdx.x, wid = tid >> 6, lane = tid & 63;

  const int nq = gridDim.x, nbh = gridDim.y;
  const int lin = blockIdx.x + nq * blockIdx.y;
  const int qb0 = lin / nbh;
  const int bh  = lin % nbh;
  const int qb  = (qb0 < nq / 2) ? qb0 : (nq + nq / 2 - 1 - qb0);

  const int b = bh / H, h = bh % H;
  const int Dh = D / H;

  const float slope2 = alibi_slope(h, H) * log2e;
  const long qrow0 = (long)b * S + qb * 64 + wid * 16;

  const int frow = lane & 15;
  const int fk8  = (lane >> 4) * 8;
  const int orow = (lane >> 4) * 4;
  const int ocol = lane & 15;

  bf16x8_t aq[4];
#pragma unroll
  for (int kk = 0; kk < 4; ++kk)
    aq[kk] = *reinterpret_cast<const bf16x8_t*>(
        Q + (qrow0 + frow) * (long)D + h * Dh + kk * 32 + fk8);

  float cw[4];
#pragma unroll
  for (int n = 0; n < 4; ++n) cw[n] = slope2 * (float)(n * 16 + ocol);

  f32x4_t oacc[8];
#pragma unroll
  for (int no = 0; no < 8; ++no)
#pragma unroll
    for (int r = 0; r < 4; ++r) oacc[no][r] = 0.f;

  float Mrun[4], lrun[4];
#pragma unroll
  for (int r = 0; r < 4; ++r) { Mrun[r] = -3.0e38f; lrun[r] = 0.f; }

  const u16* kbase = Kb + (long)b * S * D + h * Dh;
  const u16* vbase = Vt + (long)bh * Dh * S;

  const int ntile = qb + 1;

  for (int kt = 0; kt < ntile; ++kt) {
    __syncthreads();
#pragma unroll
    for (int i = 0; i < 4; ++i) {
      const int lr = i * 16 + wid * 4;
      const int r  = lr + (lane >> 4);
      gload_lds16(kbase + ((long)kt * 64 + r) * (long)D + sw8(r, (lane & 15) * 8), &Ks[lr][0]);
    }
#pragma unroll
    for (int i = 0; i < 4; ++i) {
      const int lr = i * 32 + wid * 8;
      const int r  = lr + (lane >> 3);
      gload_lds16(vbase + (long)r * S + kt * 64 + sw8(r, (lane & 7) * 8), &Vs[lr][0]);
    }
    __syncthreads();

    f32x4_t sacc[4];
#pragma unroll
    for (int n = 0; n < 4; ++n)
#pragma unroll
      for (int r = 0; r < 4; ++r) sacc[n][r] = 0.f;

#pragma unroll
    for (int kk = 0; kk < 4; ++kk) {
      bf16x8_t bk[4];
#pragma unroll
      for (int n = 0; n < 4; ++n) {
        const int krow = n * 16 + frow;
        bk[n] = *reinterpret_cast<const bf16x8_t*>(&Ks[krow][sw8(krow, kk * 32 + fk8)]);
      }
#pragma unroll
      for (int n = 0; n < 4; ++n)
        sacc[n] = __builtin_amdgcn_mfma_f32_16x16x32_bf16(aq[kk], bk[n], sacc[n], 0, 0, 0);
    }

    const float tb = slope2 * (float)(kt << 6);
    float cbn[4];
#pragma unroll
    for (int n = 0; n < 4; ++n) cbn[n] = tb + cw[n];

    float tmax[4];
#pragma unroll
    for (int r = 0; r < 4; ++r) tmax[r] = -3.0e38f;

    if (kt == qb) {
#pragma unroll
      for (int n = 0; n < 4; ++n)
#pragma unroll
        for (int r = 0; r < 4; ++r) {
          float v = sacc[n][r] + cbn[n];
          v = (n * 16 + ocol <= wid * 16 + orow + r) ? v : -1.0e30f;
          sacc[n][r] = v;
          tmax[r] = fmaxf(tmax[r], v);
        }
    } else {
#pragma unroll
      for (int n = 0; n < 4; ++n)
#pragma unroll
        for (int r = 0; r < 4; ++r) {
          const float v = sacc[n][r] + cbn[n];
          sacc[n][r] = v;
          tmax[r] = fmaxf(tmax[r], v);
        }
    }
#pragma unroll
    for (int r = 0; r < 4; ++r) {
      float t = tmax[r];
      t = fmaxf(t, __shfl_xor(t, 1));
      t = fmaxf(t, __shfl_xor(t, 2));
      t = fmaxf(t, __shfl_xor(t, 4));
      t = fmaxf(t, __shfl_xor(t, 8));
      tmax[r] = t;
    }

#pragma unroll
    for (int r = 0; r < 4; ++r) {
      const float mnew = fmaxf(Mrun[r], tmax[r]);
      const float alpha = exp2f(Mrun[r] - mnew);
      Mrun[r] = mnew;
      lrun[r] *= alpha;
#pragma unroll
      for (int no = 0; no < 8; ++no) oacc[no][r] *= alpha;
    }

    float tsum[4];
#pragma unroll
    for (int r = 0; r < 4; ++r) tsum[r] = 0.f;
#pragma unroll
    for (int n = 0; n < 4; ++n)
#pragma unroll
      for (int r = 0; r < 4; ++r) {
        const float p = exp2f(sacc[n][r] - Mrun[r]);
        tsum[r] += p;
        const int prow = wid * 16 + orow + r;
        Ps[prow][sw8(prow, n * 16 + ocol)] = f2bf(p);
      }
#pragma unroll
    for (int r = 0; r < 4; ++r) {
      float t = tsum[r];
      t += __shfl_xor(t, 1);
      t += __shfl_xor(t, 2);
      t += __shfl_xor(t, 4);
      t += __shfl_xor(t, 8);
      lrun[r] += t;
    }

    __syncthreads();

#pragma unroll
    for (int kk = 0; kk < 2; ++kk) {
      const int prow = wid * 16 + frow;
      bf16x8_t pa = *reinterpret_cast<const bf16x8_t*>(&Ps[prow][sw8(prow, kk * 32 + fk8)]);
#pragma unroll
      for (int no = 0; no < 8; ++no) {
        const int vrow = no * 16 + frow;
        bf16x8_t bv = *reinterpret_cast<const bf16x8_t*>(&Vs[vrow][sw8(vrow, kk * 32 + fk8)]);
        oacc[no] = __builtin_amdgcn_mfma_f32_16x16x32_bf16(pa, bv, oacc[no], 0, 0, 0);
      }
    }
  }

#pragma unroll
  for (int r = 0; r < 4; ++r) {
    const float rl = 1.0f / lrun[r];
    const long trow = qrow0 + orow + r;
#pragma unroll
    for (int no = 0; no < 8; ++no)
      Out[trow * (long)D + h * Dh + no * 16 + ocol] = f2bf(oacc[no][r] * rl);
  }
}

// ---- launch --------------------------------------------------------------

extern "C" void kernel_launch(void* const* d_in, const int* in_sizes, int n_in,
                              void* d_out, int out_size, void* d_ws, size_t ws_size,
                              hipStream_t stream) {
  const float* hs   = (const float*)d_in[0];
  const float* qkvw = (const float*)d_in[1];
  const float* ow   = (const float*)d_in[2];

  const int D = 2048, B = 2, H = 16;
  const long TD = (long)in_sizes[0];   // T*D = 8388608
  const long DD = (long)in_sizes[2];   // D*D = 4194304
  const int T = (int)(TD / D);         // 4096
  const int S = T / B;                 // 2048
  const int Dh = D / H;                // 128
  const float log2e = 1.44269504f;
  const float qs = (1.0f / sqrtf((float)Dh)) * log2e;  // Q prescale

  u16* ws  = (u16*)d_ws;
  u16* hsb = ws;                  // TD    (later reused as attn)
  u16* wt  = ws + TD;             // 3*DD  (later reused as vt)
  u16* owt = wt + 3 * DD;         // DD
  u16* qkv = owt + DD;            // 3*TD  [Q | K | V]
  u16* vt   = wt;                 // TD    (overlay; wt dead after QKV GEMM)
  u16* attn = hsb;                // TD    (overlay; hsb dead after QKV GEMM)

  // 1) hidden -> bf16
  k_cast_bf16<<<dim3((unsigned)(TD / 1024)), 256, 0, stream>>>(hs, hsb, TD);
  // 2) qkv weights: cast + transpose to [3][E][D] (== fused Bt [6144][2048])
  k_transpose_cast<<<dim3(D / 32, D / 32, 3), 256, 0, stream>>>(qkvw, wt, D, D);
  // 3) o_proj weight: cast + transpose to [E][D]
  k_transpose_cast<<<dim3(D / 32, D / 32, 1), 256, 0, stream>>>(ow, owt, D, D);
  // 4) fused QKV projection (Q prescaled by sm_scale*log2e in epilogue)
  k_gemm8<u16><<<dim3((3 * D) / 256, T / 256), 512, 0, stream>>>(
      hsb, wt, qkv, T, 3 * D, D, TD, qs);
  // 5) V -> Vt[bh][Dh][S]
  k_transpose_v<<<dim3(S / 32, Dh / 32, B * H), 256, 0, stream>>>(
      qkv + 2 * TD, vt, S, D, Dh, H);
  // 6) attention (QBLK=64, log2 domain)
  k_attn<<<dim3(S / 64, B * H), 256, 0, stream>>>(
      qkv, qkv + TD, vt, attn, B, S, H, D, log2e);
  // 7) output projection -> f32 d_out (m97 128x128: 16x32 = 512 blocks,
  //    2 blocks/CU co-resident, exactly 2 rounds)
  k_gemm_bt<float><<<dim3(D / 128, T / 128), 256, 0, stream>>>(
      attn, owt, (float*)d_out, T, D, D);
}